// Round 1
// baseline (1900.045 us; speedup 1.0000x reference)
//
#include <hip/hip_runtime.h>
#include <hip/hip_bf16.h>
#include <cstdint>

#define B_ 8
#define N_ 16384
#define S_ 1024
#define K_ 32
#define C_ 256
#define RR 8   // rows per knn block

__device__ __forceinline__ float gelu_f(float x){
  return 0.5f * x * (1.0f + erff(x * 0.70710678118654752f));
}

__device__ __forceinline__ float dist2_f(float px, float py, float pz,
                                         float cx, float cy, float cz){
  float dx = px - cx, dy = py - cy, dz = pz - cz;
  return dx*dx + dy*dy + dz*dz;
}

// ---------------- prep: transposes ----------------
__global__ void prep_kernel(const float* __restrict__ x,
                            const float* __restrict__ g1,
                            const float* __restrict__ g2,
                            const float* __restrict__ Wo,
                            const float* __restrict__ p2,
                            float* __restrict__ xT,
                            float* __restrict__ g1T,
                            float* __restrict__ g2T,
                            float* __restrict__ WoT,
                            float* __restrict__ p2T){
  int u = blockIdx.x * 256 + threadIdx.x;
  if (u < B_*N_){
    int b = u >> 14, n = u & (N_-1);
    const float* p = x + (size_t)u * 3;
    xT[((size_t)b*3+0)*N_ + n] = p[0];
    xT[((size_t)b*3+1)*N_ + n] = p[1];
    xT[((size_t)b*3+2)*N_ + n] = p[2];
  } else if (u < B_*N_ + 65536){
    int v = u - B_*N_; int i = v >> 8, j = v & 255;
    g1T[v] = g1[j*256 + i];
  } else if (u < B_*N_ + 2*65536){
    int v = u - B_*N_ - 65536; int i = v >> 8, j = v & 255;
    g2T[v] = g2[j*256 + i];
  } else if (u < B_*N_ + 3*65536){
    int v = u - B_*N_ - 2*65536; int i = v >> 8, j = v & 255;
    WoT[v] = Wo[j*256 + i];
  } else if (u < B_*N_ + 3*65536 + 32768){
    int v = u - B_*N_ - 3*65536; int i = v >> 8, j = v & 255;  // v = i*256+j, i<128
    p2T[v] = p2[j*128 + i];
  }
}

// ---------------- FPS: one block per batch ----------------
__global__ __launch_bounds__(1024, 4) void fps_kernel(const float* __restrict__ xT,
                                                      float* __restrict__ cent){
  int b = blockIdx.x;
  int tid = threadIdx.x;
  const float* X = xT + (size_t)b*3*N_;
  const float* Y = X + N_;
  const float* Z = Y + N_;
  float px[16], py[16], pz[16], dm[16];
  #pragma unroll
  for (int i=0;i<16;i++){
    int g = i*1024 + tid;
    px[i]=X[g]; py[i]=Y[g]; pz[i]=Z[g]; dm[i]=1e10f;
  }
  __shared__ unsigned mslot[2];
  __shared__ int islot[2];
  if (tid==0){ mslot[0]=0u; mslot[1]=0u; islot[0]=0x7FFFFFFF; islot[1]=0x7FFFFFFF; }
  __syncthreads();
  int far = 0;
  for (int s=0; s<S_; s++){
    int cur = s & 1;
    float cx = X[far], cy = Y[far], cz = Z[far];
    if (tid==0){
      float* o = cent + ((size_t)b*S_ + s)*3;
      o[0]=cx; o[1]=cy; o[2]=cz;
    }
    float m = 0.0f;
    #pragma unroll
    for (int i=0;i<16;i++){
      float d = dist2_f(px[i],py[i],pz[i],cx,cy,cz);
      dm[i] = fminf(dm[i], d);
      m = fmaxf(m, dm[i]);
    }
    // wave-level max (m becomes wave max in all lanes)
    for (int off=32; off; off>>=1) m = fmaxf(m, __shfl_xor(m, off));
    if ((tid & 63) == 0) atomicMax(&mslot[cur], __float_as_uint(m));
    __syncthreads();
    float gm = __uint_as_float(mslot[cur]);
    if (m == gm){  // wave-uniform: only candidate waves scan
      int cand = 0x7FFFFFFF;
      #pragma unroll
      for (int i=15;i>=0;i--) if (dm[i]==gm) cand = i*1024 + tid;
      if (cand != 0x7FFFFFFF) atomicMin(&islot[cur], cand);
    }
    if (tid==0){ mslot[cur^1]=0u; islot[cur^1]=0x7FFFFFFF; }
    __syncthreads();
    far = islot[cur];
  }
}

// ---------------- KNN top-32 + QKV + K-maxpool ----------------
__global__ __launch_bounds__(256) void knn_qkv_kernel(const float* __restrict__ xT,
                                                      const float* __restrict__ cent,
                                                      const float* __restrict__ Wqkv,
                                                      const float* __restrict__ bqkv,
                                                      float* __restrict__ qkv){
  __shared__ unsigned hist[RR][256];
  __shared__ unsigned candB[RR][256];
  __shared__ int      candI[RR][256];
  __shared__ int      selI[RR][32];
  __shared__ float    pts[RR][32][3];
  __shared__ int      cnt[RR];
  __shared__ int      Bstar[RR];
  int tid = threadIdx.x;
  int row0 = blockIdx.x * RR;
  int b = row0 >> 10;          // S=1024
  const float* X = xT + (size_t)b*3*N_;
  const float* Y = X + N_;
  const float* Z = Y + N_;
  float cx[RR], cy[RR], cz[RR];
  #pragma unroll
  for (int r=0;r<RR;r++){
    const float* c = cent + ((size_t)row0 + r)*3;
    cx[r]=c[0]; cy[r]=c[1]; cz[r]=c[2];
  }
  for (int i=tid; i<RR*256; i+=256) ((unsigned*)hist)[i] = 0u;
  if (tid < RR) cnt[tid]=0;
  __syncthreads();
  // pass A: coarse histogram on float-bit keys
  for (int i=0;i<64;i++){
    int g = i*256 + tid;
    float px=X[g], py=Y[g], pz=Z[g];
    #pragma unroll
    for (int r=0;r<RR;r++){
      float d = dist2_f(px,py,pz,cx[r],cy[r],cz[r]);
      int key = (int)(__float_as_uint(d) >> 20) - 840;
      key = min(max(key,0),255);
      atomicAdd(&hist[r][key], 1u);
    }
  }
  __syncthreads();
  // find B* (bin containing the 32nd smallest), one wave per row
  int w = tid >> 6, lane = tid & 63;
  for (int half=0; half<2; half++){
    int r = half*4 + w;
    uint4 h4 = ((uint4*)&hist[r][0])[lane];
    unsigned cum = h4.x + h4.y + h4.z + h4.w;
    for (int off=1; off<64; off<<=1){
      unsigned t = __shfl_up(cum, off);
      if (lane >= off) cum += t;
    }
    unsigned long long mask = __ballot(cum >= 32u);
    int lb = __ffsll((unsigned long long)mask) - 1;
    unsigned cumPrev = __shfl(cum, lb>0 ? lb-1 : 0);
    if (lane == lb){
      unsigned c0 = (lb==0) ? 0u : cumPrev;
      unsigned hh[4] = {h4.x,h4.y,h4.z,h4.w};
      int bs = lb*4 + 3;
      for (int k=0;k<4;k++){
        if (c0 + hh[k] >= 32u){ bs = lb*4 + k; break; }
        c0 += hh[k];
      }
      Bstar[r] = bs;
    }
  }
  __syncthreads();
  int bsr[RR];
  #pragma unroll
  for (int r=0;r<RR;r++) bsr[r] = min(Bstar[r]+1, 255);  // +1 margin
  // pass B: collect candidates
  for (int i=0;i<64;i++){
    int g = i*256 + tid;
    float px=X[g], py=Y[g], pz=Z[g];
    #pragma unroll
    for (int r=0;r<RR;r++){
      float d = dist2_f(px,py,pz,cx[r],cy[r],cz[r]);
      unsigned bits = __float_as_uint(d);
      int key = min(max((int)(bits>>20) - 840, 0), 255);
      if (key <= bsr[r]){
        int pos = atomicAdd(&cnt[r], 1);
        if (pos < 256){ candB[r][pos] = bits; candI[r][pos] = g; }
      }
    }
  }
  __syncthreads();
  // exact deterministic rank-select on (bits, idx), one wave per row
  for (int half=0; half<2; half++){
    int r = half*4 + w;
    int L = min(cnt[r], 256);
    for (int j=lane; j<L; j+=64){
      unsigned mb = candB[r][j]; int mi = candI[r][j];
      int rank = 0;
      for (int t=0;t<L;t++){
        unsigned tb = candB[r][t]; int ti = candI[r][t];
        rank += (tb < mb || (tb == mb && ti < mi)) ? 1 : 0;
      }
      if (rank < 32) selI[r][rank] = mi;
    }
  }
  __syncthreads();
  { int r = tid >> 5, p = tid & 31;
    int g = selI[r][p];
    pts[r][p][0]=X[g]; pts[r][p][1]=Y[g]; pts[r][p][2]=Z[g]; }
  __syncthreads();
  // qkv = max_k (Wqkv @ p_k) + b ; 3 channels per thread
  float w0[3], w1[3], w2[3], bb[3];
  #pragma unroll
  for (int c3=0;c3<3;c3++){
    int c = tid + c3*256;
    w0[c3]=Wqkv[c*3+0]; w1[c3]=Wqkv[c*3+1]; w2[c3]=Wqkv[c*3+2]; bb[c3]=bqkv[c];
  }
  for (int r=0;r<RR;r++){
    float m0=-1e30f, m1=-1e30f, m2=-1e30f;
    #pragma unroll
    for (int p=0;p<32;p++){
      float px=pts[r][p][0], py=pts[r][p][1], pz=pts[r][p][2];
      m0 = fmaxf(m0, w0[0]*px + w1[0]*py + w2[0]*pz);
      m1 = fmaxf(m1, w0[1]*px + w1[1]*py + w2[1]*pz);
      m2 = fmaxf(m2, w0[2]*px + w1[2]*py + w2[2]*pz);
    }
    float* o = qkv + ((size_t)row0 + r)*768;
    o[tid      ] = m0 + bb[0];
    o[tid + 256] = m1 + bb[1];
    o[tid + 512] = m2 + bb[2];
  }
}

// ---------------- stage 2: MLPs + softmax + output ----------------
template<int KD>
__device__ __forceinline__ void gemm_tile(const float* A_, const float* __restrict__ Wt,
                                          int rb, int lane, float acc[4][4]){
  const float4* W4 = (const float4*)Wt;
  for (int i0=0; i0<(KD>>2); i0++){
    float4 wv0 = W4[(i0*4+0)*64 + lane];
    float4 wv1 = W4[(i0*4+1)*64 + lane];
    float4 wv2 = W4[(i0*4+2)*64 + lane];
    float4 wv3 = W4[(i0*4+3)*64 + lane];
    #pragma unroll
    for (int r=0;r<4;r++){
      float4 a = ((const float4*)(A_ + (size_t)(rb+r)*KD))[i0];
      acc[r][0] = fmaf(a.x,wv0.x,fmaf(a.y,wv1.x,fmaf(a.z,wv2.x,fmaf(a.w,wv3.x,acc[r][0]))));
      acc[r][1] = fmaf(a.x,wv0.y,fmaf(a.y,wv1.y,fmaf(a.z,wv2.y,fmaf(a.w,wv3.y,acc[r][1]))));
      acc[r][2] = fmaf(a.x,wv0.z,fmaf(a.y,wv1.z,fmaf(a.z,wv2.z,fmaf(a.w,wv3.z,acc[r][2]))));
      acc[r][3] = fmaf(a.x,wv0.w,fmaf(a.y,wv1.w,fmaf(a.z,wv2.w,fmaf(a.w,wv3.w,acc[r][3]))));
    }
  }
}

__global__ __launch_bounds__(512, 2) void stage2_kernel(const float* __restrict__ qkv,
                                                        const float* __restrict__ cent,
                                                        const float* __restrict__ g1T,
                                                        const float* __restrict__ bg1,
                                                        const float* __restrict__ g2T,
                                                        const float* __restrict__ bg2,
                                                        const float* __restrict__ WoT,
                                                        const float* __restrict__ bo,
                                                        const float* __restrict__ p1,
                                                        const float* __restrict__ bp1,
                                                        const float* __restrict__ p2T,
                                                        const float* __restrict__ bp2,
                                                        float* __restrict__ out){
  __shared__ float A[32][256];
  __shared__ float T[32][128];
  __shared__ float CC[32][3];
  int tid = threadIdx.x;
  int w = tid >> 6, lane = tid & 63;
  int rb = w * 4;
  int row0 = blockIdx.x * 32;
  const float4* qkv4 = (const float4*)qkv;
  // fill A = q - k  (32 rows x 64 float4)
  #pragma unroll
  for (int t=0;t<4;t++){
    int fi = t*512 + tid;
    int r = fi >> 6, c4 = fi & 63;
    float4 q = qkv4[(size_t)(row0+r)*192 + c4];
    float4 k = qkv4[(size_t)(row0+r)*192 + 64 + c4];
    ((float4*)&A[r][0])[c4] = make_float4(q.x-k.x, q.y-k.y, q.z-k.z, q.w-k.w);
  }
  if (tid < 96) ((float*)CC)[tid] = cent[(size_t)row0*3 + tid];
  __syncthreads();
  // T = gelu(cent @ p1^T + bp1): 32x128
  #pragma unroll
  for (int t=0;t<8;t++){
    int e = t*512 + tid;
    int r = e >> 7, c = e & 127;
    float tv = CC[r][0]*p1[c*3+0] + CC[r][1]*p1[c*3+1] + CC[r][2]*p1[c*3+2] + bp1[c];
    T[r][c] = gelu_f(tv);
  }
  __syncthreads();
  // From here all rows are wave-private: no more barriers needed.
  float acc[4][4];
  // GEMM1: (q-k) @ g1T
  #pragma unroll
  for (int r=0;r<4;r++){ acc[r][0]=0.f; acc[r][1]=0.f; acc[r][2]=0.f; acc[r][3]=0.f; }
  gemm_tile<256>(&A[0][0], g1T, rb, lane, acc);
  {
    float4 bg = ((const float4*)bg1)[lane];
    #pragma unroll
    for (int r=0;r<4;r++){
      float4 g;
      g.x = gelu_f(acc[r][0] + bg.x);
      g.y = gelu_f(acc[r][1] + bg.y);
      g.z = gelu_f(acc[r][2] + bg.z);
      g.w = gelu_f(acc[r][3] + bg.w);
      ((float4*)&A[rb+r][0])[lane] = g;
    }
  }
  // GEMM2: gelu(...) @ g2T -> h; softmax(h*scale); A = attn*v
  #pragma unroll
  for (int r=0;r<4;r++){ acc[r][0]=0.f; acc[r][1]=0.f; acc[r][2]=0.f; acc[r][3]=0.f; }
  gemm_tile<256>(&A[0][0], g2T, rb, lane, acc);
  {
    float4 bg = ((const float4*)bg2)[lane];
    const float scale = 0.0625f;
    #pragma unroll
    for (int r=0;r<4;r++){
      float h0 = acc[r][0]+bg.x, h1 = acc[r][1]+bg.y, h2 = acc[r][2]+bg.z, h3 = acc[r][3]+bg.w;
      float mx = fmaxf(fmaxf(h0,h1), fmaxf(h2,h3));
      for (int off=1; off<64; off<<=1) mx = fmaxf(mx, __shfl_xor(mx, off));
      float e0 = __expf((h0-mx)*scale), e1 = __expf((h1-mx)*scale);
      float e2 = __expf((h2-mx)*scale), e3 = __expf((h3-mx)*scale);
      float sm = e0+e1+e2+e3;
      for (int off=1; off<64; off<<=1) sm += __shfl_xor(sm, off);
      float inv = 1.0f / sm;
      float4 v4 = qkv4[(size_t)(row0+rb+r)*192 + 128 + lane];
      ((float4*)&A[rb+r][0])[lane] =
          make_float4(e0*inv*v4.x, e1*inv*v4.y, e2*inv*v4.z, e3*inv*v4.w);
    }
  }
  // GEMM3: (attn*v) @ WoT  + pos (T @ p2T) + bo + bp2
  #pragma unroll
  for (int r=0;r<4;r++){ acc[r][0]=0.f; acc[r][1]=0.f; acc[r][2]=0.f; acc[r][3]=0.f; }
  gemm_tile<256>(&A[0][0], WoT, rb, lane, acc);
  gemm_tile<128>(&T[0][0], p2T, rb, lane, acc);
  {
    float4 bov = ((const float4*)bo)[lane];
    float4 bpv = ((const float4*)bp2)[lane];
    #pragma unroll
    for (int r=0;r<4;r++){
      float4 o;
      o.x = acc[r][0] + bov.x + bpv.x;
      o.y = acc[r][1] + bov.y + bpv.y;
      o.z = acc[r][2] + bov.z + bpv.z;
      o.w = acc[r][3] + bov.w + bpv.w;
      ((float4*)out)[(size_t)(row0+rb+r)*64 + lane] = o;
    }
  }
}

extern "C" void kernel_launch(void* const* d_in, const int* in_sizes, int n_in,
                              void* d_out, int out_size, void* d_ws, size_t ws_size,
                              hipStream_t stream) {
  const float* x    = (const float*)d_in[0];
  const float* Wqkv = (const float*)d_in[1];
  const float* bqkv = (const float*)d_in[2];
  const float* g1   = (const float*)d_in[3];
  const float* bg1  = (const float*)d_in[4];
  const float* g2   = (const float*)d_in[5];
  const float* bg2  = (const float*)d_in[6];
  const float* Wo   = (const float*)d_in[7];
  const float* bo   = (const float*)d_in[8];
  const float* p1   = (const float*)d_in[9];
  const float* bp1  = (const float*)d_in[10];
  const float* p2   = (const float*)d_in[11];
  const float* bp2  = (const float*)d_in[12];
  float* out = (float*)d_out;
  float* ws = (float*)d_ws;

  float* xT   = ws;                      // 393216
  float* cent = xT + 393216;             // 24576
  float* qkv  = cent + 24576;            // 6291456
  float* g1T  = qkv + 6291456;           // 65536
  float* g2T  = g1T + 65536;             // 65536
  float* WoT  = g2T + 65536;             // 65536
  float* p2T  = WoT + 65536;             // 32768

  hipLaunchKernelGGL(prep_kernel, dim3(1408), dim3(256), 0, stream,
                     x, g1, g2, Wo, p2, xT, g1T, g2T, WoT, p2T);
  hipLaunchKernelGGL(fps_kernel, dim3(B_), dim3(1024), 0, stream, xT, cent);
  hipLaunchKernelGGL(knn_qkv_kernel, dim3(B_*S_/RR), dim3(256), 0, stream,
                     xT, cent, Wqkv, bqkv, qkv);
  hipLaunchKernelGGL(stage2_kernel, dim3(B_*S_/32), dim3(512), 0, stream,
                     qkv, cent, g1T, bg1, g2T, bg2, WoT, bo, p1, bp1, p2T, bp2, out);
}

// Round 2
// 1667.812 us; speedup vs baseline: 1.1392x; 1.1392x over previous
//
#include <hip/hip_runtime.h>
#include <hip/hip_bf16.h>
#include <cstdint>

#define B_ 8
#define N_ 16384
#define S_ 1024
#define K_ 32
#define C_ 256
#define RR 8   // rows per knn block

__device__ __forceinline__ float gelu_f(float x){
  return 0.5f * x * (1.0f + erff(x * 0.70710678118654752f));
}

__device__ __forceinline__ float dist2_f(float px, float py, float pz,
                                         float cx, float cy, float cz){
  float dx = px - cx, dy = py - cy, dz = pz - cz;
  return dx*dx + dy*dy + dz*dz;
}

// ---------------- prep: transposes + AoS float4 ----------------
__global__ void prep_kernel(const float* __restrict__ x,
                            const float* __restrict__ g1,
                            const float* __restrict__ g2,
                            const float* __restrict__ Wo,
                            const float* __restrict__ p2,
                            float* __restrict__ xT,
                            float* __restrict__ g1T,
                            float* __restrict__ g2T,
                            float* __restrict__ WoT,
                            float* __restrict__ p2T,
                            float4* __restrict__ xP){
  int u = blockIdx.x * 256 + threadIdx.x;
  if (u < B_*N_){
    int b = u >> 14, n = u & (N_-1);
    const float* p = x + (size_t)u * 3;
    float X = p[0], Y = p[1], Z = p[2];
    xT[((size_t)b*3+0)*N_ + n] = X;
    xT[((size_t)b*3+1)*N_ + n] = Y;
    xT[((size_t)b*3+2)*N_ + n] = Z;
    xP[u] = make_float4(X, Y, Z, X*X + Y*Y + Z*Z);
  } else if (u < B_*N_ + 65536){
    int v = u - B_*N_; int i = v >> 8, j = v & 255;
    g1T[v] = g1[j*256 + i];
  } else if (u < B_*N_ + 2*65536){
    int v = u - B_*N_ - 65536; int i = v >> 8, j = v & 255;
    g2T[v] = g2[j*256 + i];
  } else if (u < B_*N_ + 3*65536){
    int v = u - B_*N_ - 2*65536; int i = v >> 8, j = v & 255;
    WoT[v] = Wo[j*256 + i];
  } else if (u < B_*N_ + 3*65536 + 32768){
    int v = u - B_*N_ - 3*65536; int i = v >> 8, j = v & 255;  // v = i*256+j, i<128
    p2T[v] = p2[j*128 + i];
  }
}

// ---------------- FPS: one block per batch, register-resident ----------------
__global__ __launch_bounds__(512, 2) void fps_kernel(const float4* __restrict__ xP,
                                                     float* __restrict__ cent){
  int b = blockIdx.x;
  int tid = threadIdx.x;           // 0..511
  int w = tid >> 6, lane = tid & 63;
  const float4* P = xP + (size_t)b * N_;
  float px[32], py[32], pz[32], dm[32];
  #pragma unroll
  for (int i=0;i<32;i++){
    float4 p = P[i*512 + tid];
    px[i]=p.x; py[i]=p.y; pz[i]=p.z; dm[i]=1e10f;
  }
  __shared__ float wmax[8];
  __shared__ int islot[2];
  __shared__ float centb[S_*3];
  if (tid < 2) islot[tid] = 0x7FFFFFFF;
  __syncthreads();
  float4 c4 = P[0];
  for (int s=0; s<S_; s++){
    int cur = s & 1;
    if (tid == 0){
      centb[s*3+0]=c4.x; centb[s*3+1]=c4.y; centb[s*3+2]=c4.z;
    }
    float cx=c4.x, cy=c4.y, cz=c4.z;
    // update dm
    #pragma unroll
    for (int i=0;i<32;i++){
      float dx=px[i]-cx, dy=py[i]-cy, dz=pz[i]-cz;
      float d = fmaf(dz,dz, fmaf(dy,dy, dx*dx));
      dm[i] = fminf(dm[i], d);
    }
    // lane-local max (pairwise tree)
    float tt[16];
    #pragma unroll
    for (int i=0;i<16;i++) tt[i] = fmaxf(dm[2*i], dm[2*i+1]);
    #pragma unroll
    for (int i=0;i<8;i++) tt[i] = fmaxf(tt[i], tt[i+8]);
    #pragma unroll
    for (int i=0;i<4;i++) tt[i] = fmaxf(tt[i], tt[i+4]);
    float ml = fmaxf(fmaxf(tt[0],tt[1]), fmaxf(tt[2],tt[3]));
    // wave max
    float wm = ml;
    for (int off=32; off; off>>=1) wm = fmaxf(wm, __shfl_xor(wm, off));
    if (lane == 0) wmax[w] = wm;
    if (tid == 0) islot[cur^1] = 0x7FFFFFFF;   // reset other buffer
    __syncthreads();
    float g0 = fmaxf(fmaxf(wmax[0],wmax[1]), fmaxf(wmax[2],wmax[3]));
    float g1 = fmaxf(fmaxf(wmax[4],wmax[5]), fmaxf(wmax[6],wmax[7]));
    float gm = fmaxf(g0, g1);
    if (wm == gm){                 // wave-uniform branch: only candidate wave(s)
      int cidx = 0x7FFFFFFF;
      #pragma unroll
      for (int i=0;i<32;i++){
        int idxi = i*512 + tid;
        cidx = min(cidx, (dm[i]==gm) ? idxi : 0x7FFFFFFF);
      }
      if (cidx != 0x7FFFFFFF) atomicMin(&islot[cur], cidx);
    }
    __syncthreads();
    int far = islot[cur];
    c4 = P[far];                   // single b128, same addr across lanes
  }
  __syncthreads();
  for (int i = tid; i < S_*3; i += 512) cent[(size_t)b*S_*3 + i] = centb[i];
}

// ---------------- KNN top-32 + QKV + K-maxpool ----------------
__global__ __launch_bounds__(256) void knn_qkv_kernel(const float* __restrict__ xT,
                                                      const float* __restrict__ cent,
                                                      const float* __restrict__ Wqkv,
                                                      const float* __restrict__ bqkv,
                                                      float* __restrict__ qkv){
  __shared__ unsigned hist[RR][256];
  __shared__ unsigned candB[RR][256];
  __shared__ int      candI[RR][256];
  __shared__ int      selI[RR][32];
  __shared__ float    pts[RR][32][3];
  __shared__ int      cnt[RR];
  __shared__ int      Bstar[RR];
  int tid = threadIdx.x;
  int row0 = blockIdx.x * RR;
  int b = row0 >> 10;          // S=1024
  const float* X = xT + (size_t)b*3*N_;
  const float* Y = X + N_;
  const float* Z = Y + N_;
  float cx[RR], cy[RR], cz[RR];
  #pragma unroll
  for (int r=0;r<RR;r++){
    const float* c = cent + ((size_t)row0 + r)*3;
    cx[r]=c[0]; cy[r]=c[1]; cz[r]=c[2];
  }
  for (int i=tid; i<RR*256; i+=256) ((unsigned*)hist)[i] = 0u;
  if (tid < RR) cnt[tid]=0;
  __syncthreads();
  // pass A: coarse histogram on float-bit keys
  for (int i=0;i<64;i++){
    int g = i*256 + tid;
    float px=X[g], py=Y[g], pz=Z[g];
    #pragma unroll
    for (int r=0;r<RR;r++){
      float d = dist2_f(px,py,pz,cx[r],cy[r],cz[r]);
      int key = (int)(__float_as_uint(d) >> 20) - 840;
      key = min(max(key,0),255);
      atomicAdd(&hist[r][key], 1u);
    }
  }
  __syncthreads();
  // find B* (bin containing the 32nd smallest), one wave per row
  int w = tid >> 6, lane = tid & 63;
  for (int half=0; half<2; half++){
    int r = half*4 + w;
    uint4 h4 = ((uint4*)&hist[r][0])[lane];
    unsigned cum = h4.x + h4.y + h4.z + h4.w;
    for (int off=1; off<64; off<<=1){
      unsigned t = __shfl_up(cum, off);
      if (lane >= off) cum += t;
    }
    unsigned long long mask = __ballot(cum >= 32u);
    int lb = __ffsll((unsigned long long)mask) - 1;
    unsigned cumPrev = __shfl(cum, lb>0 ? lb-1 : 0);
    if (lane == lb){
      unsigned c0 = (lb==0) ? 0u : cumPrev;
      unsigned hh[4] = {h4.x,h4.y,h4.z,h4.w};
      int bs = lb*4 + 3;
      for (int k=0;k<4;k++){
        if (c0 + hh[k] >= 32u){ bs = lb*4 + k; break; }
        c0 += hh[k];
      }
      Bstar[r] = bs;
    }
  }
  __syncthreads();
  int bsr[RR];
  #pragma unroll
  for (int r=0;r<RR;r++) bsr[r] = min(Bstar[r]+1, 255);  // +1 margin
  // pass B: collect candidates
  for (int i=0;i<64;i++){
    int g = i*256 + tid;
    float px=X[g], py=Y[g], pz=Z[g];
    #pragma unroll
    for (int r=0;r<RR;r++){
      float d = dist2_f(px,py,pz,cx[r],cy[r],cz[r]);
      unsigned bits = __float_as_uint(d);
      int key = min(max((int)(bits>>20) - 840, 0), 255);
      if (key <= bsr[r]){
        int pos = atomicAdd(&cnt[r], 1);
        if (pos < 256){ candB[r][pos] = bits; candI[r][pos] = g; }
      }
    }
  }
  __syncthreads();
  // exact deterministic rank-select on (bits, idx), one wave per row
  for (int half=0; half<2; half++){
    int r = half*4 + w;
    int L = min(cnt[r], 256);
    for (int j=lane; j<L; j+=64){
      unsigned mb = candB[r][j]; int mi = candI[r][j];
      int rank = 0;
      for (int t=0;t<L;t++){
        unsigned tb = candB[r][t]; int ti = candI[r][t];
        rank += (tb < mb || (tb == mb && ti < mi)) ? 1 : 0;
      }
      if (rank < 32) selI[r][rank] = mi;
    }
  }
  __syncthreads();
  { int r = tid >> 5, p = tid & 31;
    int g = selI[r][p];
    pts[r][p][0]=X[g]; pts[r][p][1]=Y[g]; pts[r][p][2]=Z[g]; }
  __syncthreads();
  // qkv = max_k (Wqkv @ p_k) + b ; 3 channels per thread
  float w0[3], w1[3], w2[3], bb[3];
  #pragma unroll
  for (int c3=0;c3<3;c3++){
    int c = tid + c3*256;
    w0[c3]=Wqkv[c*3+0]; w1[c3]=Wqkv[c*3+1]; w2[c3]=Wqkv[c*3+2]; bb[c3]=bqkv[c];
  }
  for (int r=0;r<RR;r++){
    float m0=-1e30f, m1=-1e30f, m2=-1e30f;
    #pragma unroll
    for (int p=0;p<32;p++){
      float px=pts[r][p][0], py=pts[r][p][1], pz=pts[r][p][2];
      m0 = fmaxf(m0, w0[0]*px + w1[0]*py + w2[0]*pz);
      m1 = fmaxf(m1, w0[1]*px + w1[1]*py + w2[1]*pz);
      m2 = fmaxf(m2, w0[2]*px + w1[2]*py + w2[2]*pz);
    }
    float* o = qkv + ((size_t)row0 + r)*768;
    o[tid      ] = m0 + bb[0];
    o[tid + 256] = m1 + bb[1];
    o[tid + 512] = m2 + bb[2];
  }
}

// ---------------- stage 2: MLPs + softmax + output ----------------
template<int KD>
__device__ __forceinline__ void gemm_tile(const float* A_, const float* __restrict__ Wt,
                                          int rb, int lane, float acc[4][4]){
  const float4* W4 = (const float4*)Wt;
  for (int i0=0; i0<(KD>>2); i0++){
    float4 wv0 = W4[(i0*4+0)*64 + lane];
    float4 wv1 = W4[(i0*4+1)*64 + lane];
    float4 wv2 = W4[(i0*4+2)*64 + lane];
    float4 wv3 = W4[(i0*4+3)*64 + lane];
    #pragma unroll
    for (int r=0;r<4;r++){
      float4 a = ((const float4*)(A_ + (size_t)(rb+r)*KD))[i0];
      acc[r][0] = fmaf(a.x,wv0.x,fmaf(a.y,wv1.x,fmaf(a.z,wv2.x,fmaf(a.w,wv3.x,acc[r][0]))));
      acc[r][1] = fmaf(a.x,wv0.y,fmaf(a.y,wv1.y,fmaf(a.z,wv2.y,fmaf(a.w,wv3.y,acc[r][1]))));
      acc[r][2] = fmaf(a.x,wv0.z,fmaf(a.y,wv1.z,fmaf(a.z,wv2.z,fmaf(a.w,wv3.z,acc[r][2]))));
      acc[r][3] = fmaf(a.x,wv0.w,fmaf(a.y,wv1.w,fmaf(a.z,wv2.w,fmaf(a.w,wv3.w,acc[r][3]))));
    }
  }
}

__global__ __launch_bounds__(512, 2) void stage2_kernel(const float* __restrict__ qkv,
                                                        const float* __restrict__ cent,
                                                        const float* __restrict__ g1T,
                                                        const float* __restrict__ bg1,
                                                        const float* __restrict__ g2T,
                                                        const float* __restrict__ bg2,
                                                        const float* __restrict__ WoT,
                                                        const float* __restrict__ bo,
                                                        const float* __restrict__ p1,
                                                        const float* __restrict__ bp1,
                                                        const float* __restrict__ p2T,
                                                        const float* __restrict__ bp2,
                                                        float* __restrict__ out){
  __shared__ float A[32][256];
  __shared__ float T[32][128];
  __shared__ float CC[32][3];
  int tid = threadIdx.x;
  int w = tid >> 6, lane = tid & 63;
  int rb = w * 4;
  int row0 = blockIdx.x * 32;
  const float4* qkv4 = (const float4*)qkv;
  // fill A = q - k  (32 rows x 64 float4)
  #pragma unroll
  for (int t=0;t<4;t++){
    int fi = t*512 + tid;
    int r = fi >> 6, c4 = fi & 63;
    float4 q = qkv4[(size_t)(row0+r)*192 + c4];
    float4 k = qkv4[(size_t)(row0+r)*192 + 64 + c4];
    ((float4*)&A[r][0])[c4] = make_float4(q.x-k.x, q.y-k.y, q.z-k.z, q.w-k.w);
  }
  if (tid < 96) ((float*)CC)[tid] = cent[(size_t)row0*3 + tid];
  __syncthreads();
  // T = gelu(cent @ p1^T + bp1): 32x128
  #pragma unroll
  for (int t=0;t<8;t++){
    int e = t*512 + tid;
    int r = e >> 7, c = e & 127;
    float tv = CC[r][0]*p1[c*3+0] + CC[r][1]*p1[c*3+1] + CC[r][2]*p1[c*3+2] + bp1[c];
    T[r][c] = gelu_f(tv);
  }
  __syncthreads();
  // From here all rows are wave-private: no more barriers needed.
  float acc[4][4];
  // GEMM1: (q-k) @ g1T
  #pragma unroll
  for (int r=0;r<4;r++){ acc[r][0]=0.f; acc[r][1]=0.f; acc[r][2]=0.f; acc[r][3]=0.f; }
  gemm_tile<256>(&A[0][0], g1T, rb, lane, acc);
  {
    float4 bg = ((const float4*)bg1)[lane];
    #pragma unroll
    for (int r=0;r<4;r++){
      float4 g;
      g.x = gelu_f(acc[r][0] + bg.x);
      g.y = gelu_f(acc[r][1] + bg.y);
      g.z = gelu_f(acc[r][2] + bg.z);
      g.w = gelu_f(acc[r][3] + bg.w);
      ((float4*)&A[rb+r][0])[lane] = g;
    }
  }
  // GEMM2: gelu(...) @ g2T -> h; softmax(h*scale); A = attn*v
  #pragma unroll
  for (int r=0;r<4;r++){ acc[r][0]=0.f; acc[r][1]=0.f; acc[r][2]=0.f; acc[r][3]=0.f; }
  gemm_tile<256>(&A[0][0], g2T, rb, lane, acc);
  {
    float4 bg = ((const float4*)bg2)[lane];
    const float scale = 0.0625f;
    #pragma unroll
    for (int r=0;r<4;r++){
      float h0 = acc[r][0]+bg.x, h1 = acc[r][1]+bg.y, h2 = acc[r][2]+bg.z, h3 = acc[r][3]+bg.w;
      float mx = fmaxf(fmaxf(h0,h1), fmaxf(h2,h3));
      for (int off=1; off<64; off<<=1) mx = fmaxf(mx, __shfl_xor(mx, off));
      float e0 = __expf((h0-mx)*scale), e1 = __expf((h1-mx)*scale);
      float e2 = __expf((h2-mx)*scale), e3 = __expf((h3-mx)*scale);
      float sm = e0+e1+e2+e3;
      for (int off=1; off<64; off<<=1) sm += __shfl_xor(sm, off);
      float inv = 1.0f / sm;
      float4 v4 = qkv4[(size_t)(row0+rb+r)*192 + 128 + lane];
      ((float4*)&A[rb+r][0])[lane] =
          make_float4(e0*inv*v4.x, e1*inv*v4.y, e2*inv*v4.z, e3*inv*v4.w);
    }
  }
  // GEMM3: (attn*v) @ WoT  + pos (T @ p2T) + bo + bp2
  #pragma unroll
  for (int r=0;r<4;r++){ acc[r][0]=0.f; acc[r][1]=0.f; acc[r][2]=0.f; acc[r][3]=0.f; }
  gemm_tile<256>(&A[0][0], WoT, rb, lane, acc);
  gemm_tile<128>(&T[0][0], p2T, rb, lane, acc);
  {
    float4 bov = ((const float4*)bo)[lane];
    float4 bpv = ((const float4*)bp2)[lane];
    #pragma unroll
    for (int r=0;r<4;r++){
      float4 o;
      o.x = acc[r][0] + bov.x + bpv.x;
      o.y = acc[r][1] + bov.y + bpv.y;
      o.z = acc[r][2] + bov.z + bpv.z;
      o.w = acc[r][3] + bov.w + bpv.w;
      ((float4*)out)[(size_t)(row0+rb+r)*64 + lane] = o;
    }
  }
}

extern "C" void kernel_launch(void* const* d_in, const int* in_sizes, int n_in,
                              void* d_out, int out_size, void* d_ws, size_t ws_size,
                              hipStream_t stream) {
  const float* x    = (const float*)d_in[0];
  const float* Wqkv = (const float*)d_in[1];
  const float* bqkv = (const float*)d_in[2];
  const float* g1   = (const float*)d_in[3];
  const float* bg1  = (const float*)d_in[4];
  const float* g2   = (const float*)d_in[5];
  const float* bg2  = (const float*)d_in[6];
  const float* Wo   = (const float*)d_in[7];
  const float* bo   = (const float*)d_in[8];
  const float* p1   = (const float*)d_in[9];
  const float* bp1  = (const float*)d_in[10];
  const float* p2   = (const float*)d_in[11];
  const float* bp2  = (const float*)d_in[12];
  float* out = (float*)d_out;
  float* ws = (float*)d_ws;

  float* xT   = ws;                      // 393216 floats
  float* cent = xT + 393216;             // 24576
  float* qkv  = cent + 24576;            // 6291456
  float* g1T  = qkv + 6291456;           // 65536
  float* g2T  = g1T + 65536;             // 65536
  float* WoT  = g2T + 65536;             // 65536
  float* p2T  = WoT + 65536;             // 32768
  float4* xP  = (float4*)(p2T + 32768);  // 131072 float4 = 524288 floats

  hipLaunchKernelGGL(prep_kernel, dim3(1408), dim3(256), 0, stream,
                     x, g1, g2, Wo, p2, xT, g1T, g2T, WoT, p2T, xP);
  hipLaunchKernelGGL(fps_kernel, dim3(B_), dim3(512), 0, stream, xP, cent);
  hipLaunchKernelGGL(knn_qkv_kernel, dim3(B_*S_/RR), dim3(256), 0, stream,
                     xT, cent, Wqkv, bqkv, qkv);
  hipLaunchKernelGGL(stage2_kernel, dim3(B_*S_/32), dim3(512), 0, stream,
                     qkv, cent, g1T, bg1, g2T, bg2, WoT, bo, p1, bp1, p2T, bp2, out);
}